// Round 10
// baseline (425.465 us; speedup 1.0000x reference)
//
#include <hip/hip_runtime.h>
#include <hip/hip_bf16.h>

#define N_NODES 50000
#define N_EDGES 625000
#define IN_DIM  300
#define KPAD    320   // IN_DIM padded to multiple of 32
#define HID     128
#define NLAYERS 4

#define SB      256                            // scan block size
#define NCH     ((N_NODES + SB - 1) / SB)      // 196 chunks

typedef __hip_bfloat16 bf16;
typedef __attribute__((ext_vector_type(8))) short short8;   // 8 bf16 = 4 VGPRs
typedef __attribute__((ext_vector_type(4))) float f32x4;

__device__ inline short f2bf(float v) {
    bf16 t = __float2bfloat16(v);
    return *reinterpret_cast<short*>(&t);
}
__device__ inline unsigned short f2bfu(float v) {
    bf16 t = __float2bfloat16(v);
    return *reinterpret_cast<unsigned short*>(&t);
}
__device__ inline float bflo(unsigned v) { return __uint_as_float((v & 0xffffu) << 16); }
__device__ inline float bfhi(unsigned v) { return __uint_as_float(v & 0xffff0000u); }

// ---------------- degree histogram (int) ----------------
__global__ void k_deg(const int* __restrict__ dst, int* __restrict__ deg) {
    int e = blockIdx.x * blockDim.x + threadIdx.x;
    if (e < N_EDGES) atomicAdd(&deg[dst[e]], 1);
}

// ---------------- hierarchical scan: deg -> exclusive prefix ----------------
__global__ void k_scan1(const int* __restrict__ deg, int* __restrict__ bsum) {
    const int i = blockIdx.x * SB + threadIdx.x;
    int v = (i < N_NODES) ? deg[i] : 0;
#pragma unroll
    for (int off = 32; off > 0; off >>= 1) v += __shfl_down(v, off);
    __shared__ int wsum[SB / 64];
    if ((threadIdx.x & 63) == 0) wsum[threadIdx.x >> 6] = v;
    __syncthreads();
    if (threadIdx.x == 0) {
        int s = 0;
#pragma unroll
        for (int w = 0; w < SB / 64; w++) s += wsum[w];
        bsum[blockIdx.x] = s;
    }
}

__global__ void k_scan2(const int* __restrict__ bsum, int* __restrict__ boff) {
    __shared__ int s[SB];
    const int t = threadIdx.x;
    int v = (t < NCH) ? bsum[t] : 0;
    s[t] = v;
    __syncthreads();
    for (int off = 1; off < SB; off <<= 1) {
        int u = (t >= off) ? s[t - off] : 0;
        __syncthreads();
        s[t] += u;
        __syncthreads();
    }
    if (t < NCH) boff[t] = s[t] - v;   // exclusive
}

__global__ void k_scan3(const int* __restrict__ deg, const int* __restrict__ boff,
                        int* __restrict__ rowcur) {
    __shared__ int s[SB];
    const int b = blockIdx.x, t = threadIdx.x;
    const int i = b * SB + t;
    int v = (i < N_NODES) ? deg[i] : 0;
    s[t] = v;
    __syncthreads();
    for (int off = 1; off < SB; off <<= 1) {
        int u = (t >= off) ? s[t - off] : 0;
        __syncthreads();
        s[t] += u;
        __syncthreads();
    }
    if (i < N_NODES) rowcur[i] = boff[b] + s[t] - v;   // exclusive
}

// ---------------- deg(int) -> 1/max(deg,1) (float, in place) ----------------
__global__ void k_invdeg(int* degbuf) {
    int i = blockIdx.x * blockDim.x + threadIdx.x;
    if (i < N_NODES) {
        int d = degbuf[i];
        float inv = 1.0f / (float)max(d, 1);
        ((float*)degbuf)[i] = inv;
    }
}

// ---------------- CSR fill ----------------
__global__ void k_fill(const int* __restrict__ src, const int* __restrict__ dst,
                       int* __restrict__ rowcur, int* __restrict__ csr_src) {
    int e = blockIdx.x * blockDim.x + threadIdx.x;
    if (e < N_EDGES) {
        int d = dst[e];
        int pos = atomicAdd(&rowcur[d], 1);
        csr_src[pos] = src[e];
    }
}

// ---------------- Wl/Wr -> W^T bf16 ----------------
__global__ void k_wconv(const float* __restrict__ Wl, const float* __restrict__ Wr,
                        bf16* __restrict__ WlT, bf16* __restrict__ WrT) {
    int idx = blockIdx.x * 256 + threadIdx.x;
    if (idx >= NLAYERS * HID * HID) return;
    int l = idx / (HID * HID);
    int rem = idx - l * HID * HID;
    int k = rem >> 7;
    int f = rem & 127;
    size_t o = (size_t)l * HID * HID + (size_t)f * HID + k;
    WlT[o] = __float2bfloat16(Wl[idx]);
    WrT[o] = __float2bfloat16(Wr[idx]);
}

// ---------------- emb_W[300][128] -> embT[128][KPAD] bf16 (zero-padded K) ----------------
__global__ void k_wembT(const float* __restrict__ W, bf16* __restrict__ embT) {
    int idx = blockIdx.x * 256 + threadIdx.x;
    if (idx >= HID * KPAD) return;
    int f = idx / KPAD, k = idx - f * KPAD;
    float v = (k < IN_DIM) ? W[(size_t)k * HID + f] : 0.0f;
    embT[idx] = __float2bfloat16(v);
}

// ---------------- embedding via MFMA (measured ~53 us) ----------------
__global__ __launch_bounds__(256, 4)
void k_embed_mfma(const float* __restrict__ x, const bf16* __restrict__ embT,
                  const float* __restrict__ b, bf16* __restrict__ h) {
    const int wid  = threadIdx.x >> 6;
    const int lane = threadIdx.x & 63;
    const int r0   = blockIdx.x * 64 + wid * 16;
    const int lrow = lane & 15;
    const int kgrp = lane >> 4;

    const int arow = min(r0 + lrow, N_NODES - 1);
    const float* xrow = x + (size_t)arow * IN_DIM;

    f32x4 acc[8];
#pragma unroll
    for (int c = 0; c < 8; c++) acc[c] = (f32x4){0.f, 0.f, 0.f, 0.f};

    for (int kk = 0; kk < KPAD / 32; kk++) {
        const int k0 = kk * 32 + kgrp * 8;
        short8 a;
        if (kk < 9) {
            float4 f0 = *reinterpret_cast<const float4*>(xrow + k0);
            float4 f1 = *reinterpret_cast<const float4*>(xrow + k0 + 4);
            a[0] = f2bf(f0.x); a[1] = f2bf(f0.y); a[2] = f2bf(f0.z); a[3] = f2bf(f0.w);
            a[4] = f2bf(f1.x); a[5] = f2bf(f1.y); a[6] = f2bf(f1.z); a[7] = f2bf(f1.w);
        } else {
#pragma unroll
            for (int j = 0; j < 8; j++) {
                int k = k0 + j;
                a[j] = f2bf((k < IN_DIM) ? xrow[k] : 0.0f);
            }
        }
#pragma unroll
        for (int c = 0; c < 8; c++) {
            short8 bfrag = *reinterpret_cast<const short8*>(embT + (size_t)(c * 16 + lrow) * KPAD + k0);
            acc[c] = __builtin_amdgcn_mfma_f32_16x16x32_bf16(a, bfrag, acc[c], 0, 0, 0);
        }
    }

#pragma unroll
    for (int c = 0; c < 8; c++) {
        const int col = c * 16 + lrow;
        const float bias = b[col];
#pragma unroll
        for (int r = 0; r < 4; r++) {
            const int row = r0 + kgrp * 4 + r;
            if (row < N_NODES)
                h[(size_t)row * HID + col] = __float2bfloat16(fmaxf(acc[c][r] + bias, 0.0f));
        }
    }
}

// ---------------- per-row uint8 quantization of h (h >= 0 after relu) ----------------
// one wave per node: row max via shfl, q = rint(v * 255/max), scale = max/255
__global__ void k_quant(const bf16* __restrict__ h, unsigned char* __restrict__ q8,
                        float* __restrict__ qs) {
    const int node = blockIdx.x * (blockDim.x >> 6) + (threadIdx.x >> 6);
    if (node >= N_NODES) return;
    const int lane = threadIdx.x & 63;
    unsigned v = *reinterpret_cast<const unsigned*>(h + (size_t)node * HID + lane * 2);
    float f0 = bflo(v), f1 = bfhi(v);
    float m = fmaxf(f0, f1);
#pragma unroll
    for (int off = 1; off < 64; off <<= 1) m = fmaxf(m, __shfl_xor(m, off));
    const float inv = (m > 0.0f) ? (255.0f / m) : 0.0f;
    unsigned q0 = (unsigned)rintf(f0 * inv);
    unsigned q1 = (unsigned)rintf(f1 * inv);
    *reinterpret_cast<unsigned short*>(q8 + (size_t)node * HID + lane * 2) =
        (unsigned short)(q0 | (q1 << 8));
    if (lane == 0) qs[node] = m * (1.0f / 255.0f);
}

// ---------------- gather-aggregate over uint8 rows: quarter-wave per edge, 8B/lane ----
// agg[n] = (sum_e q8[src_e] * qs[src_e]) * invdeg[n], written as bf16
__global__ void k_gather(const int* __restrict__ rowend, const int* __restrict__ csr_src,
                         const unsigned char* __restrict__ q8, const float* __restrict__ qs,
                         const float* __restrict__ invdeg, bf16* __restrict__ agg) {
    const int node = blockIdx.x * (blockDim.x >> 6) + (threadIdx.x >> 6);
    if (node >= N_NODES) return;
    const int lane = threadIdx.x & 63;
    const int g    = lane >> 4;
    const int fl   = lane & 15;
    const int beg = (node == 0) ? 0 : rowend[node - 1];
    const int end = rowend[node];

    float a0 = 0.f, a1 = 0.f, a2 = 0.f, a3 = 0.f;
    float a4 = 0.f, a5 = 0.f, a6 = 0.f, a7 = 0.f;
    float c0 = 0.f, c1 = 0.f, c2 = 0.f, c3 = 0.f;
    float c4 = 0.f, c5 = 0.f, c6 = 0.f, c7 = 0.f;

#define DQA(vv, sc) { \
        unsigned lo_ = vv.x, hi_ = vv.y; \
        a0 = fmaf((float)(lo_ & 255u), sc, a0); \
        a1 = fmaf((float)((lo_ >> 8) & 255u), sc, a1); \
        a2 = fmaf((float)((lo_ >> 16) & 255u), sc, a2); \
        a3 = fmaf((float)(lo_ >> 24), sc, a3); \
        a4 = fmaf((float)(hi_ & 255u), sc, a4); \
        a5 = fmaf((float)((hi_ >> 8) & 255u), sc, a5); \
        a6 = fmaf((float)((hi_ >> 16) & 255u), sc, a6); \
        a7 = fmaf((float)(hi_ >> 24), sc, a7); }
#define DQC(vv, sc) { \
        unsigned lo_ = vv.x, hi_ = vv.y; \
        c0 = fmaf((float)(lo_ & 255u), sc, c0); \
        c1 = fmaf((float)((lo_ >> 8) & 255u), sc, c1); \
        c2 = fmaf((float)((lo_ >> 16) & 255u), sc, c2); \
        c3 = fmaf((float)(lo_ >> 24), sc, c3); \
        c4 = fmaf((float)(hi_ & 255u), sc, c4); \
        c5 = fmaf((float)((hi_ >> 8) & 255u), sc, c5); \
        c6 = fmaf((float)((hi_ >> 16) & 255u), sc, c6); \
        c7 = fmaf((float)(hi_ >> 24), sc, c7); }

    int e = beg;
    for (; e + 16 <= end; e += 16) {        // 16 edges in flight per wave
        int s0 = csr_src[e + g];
        int s1 = csr_src[e + 4 + g];
        int s2 = csr_src[e + 8 + g];
        int s3 = csr_src[e + 12 + g];
        uint2 v0 = *reinterpret_cast<const uint2*>(q8 + (size_t)s0 * HID + fl * 8);
        uint2 v1 = *reinterpret_cast<const uint2*>(q8 + (size_t)s1 * HID + fl * 8);
        uint2 v2 = *reinterpret_cast<const uint2*>(q8 + (size_t)s2 * HID + fl * 8);
        uint2 v3 = *reinterpret_cast<const uint2*>(q8 + (size_t)s3 * HID + fl * 8);
        float sc0 = qs[s0], sc1 = qs[s1], sc2 = qs[s2], sc3 = qs[s3];
        DQA(v0, sc0); DQC(v1, sc1); DQA(v2, sc2); DQC(v3, sc3);
    }
    for (; e + 4 <= end; e += 4) {
        int s0 = csr_src[e + g];
        uint2 v0 = *reinterpret_cast<const uint2*>(q8 + (size_t)s0 * HID + fl * 8);
        float sc0 = qs[s0];
        DQA(v0, sc0);
    }
    if (e < end) {                           // tail: 1..3 edges, per-group predicated
        int idx = e + g;
        bool valid = idx < end;
        int s = csr_src[valid ? idx : end - 1];
        uint2 v = *reinterpret_cast<const uint2*>(q8 + (size_t)s * HID + fl * 8);
        float sc = valid ? qs[s] : 0.0f;
        DQA(v, sc);
    }
#undef DQA
#undef DQC
    a0 += c0; a1 += c1; a2 += c2; a3 += c3;
    a4 += c4; a5 += c5; a6 += c6; a7 += c7;

    // reduce across the 4 groups (lanes differing in bits 4,5)
    a0 += __shfl_xor(a0, 16); a1 += __shfl_xor(a1, 16);
    a2 += __shfl_xor(a2, 16); a3 += __shfl_xor(a3, 16);
    a4 += __shfl_xor(a4, 16); a5 += __shfl_xor(a5, 16);
    a6 += __shfl_xor(a6, 16); a7 += __shfl_xor(a7, 16);
    a0 += __shfl_xor(a0, 32); a1 += __shfl_xor(a1, 32);
    a2 += __shfl_xor(a2, 32); a3 += __shfl_xor(a3, 32);
    a4 += __shfl_xor(a4, 32); a5 += __shfl_xor(a5, 32);
    a6 += __shfl_xor(a6, 32); a7 += __shfl_xor(a7, 32);

    if (g == 0) {
        const float id = invdeg[node];
        uint4 o;
        o.x = (unsigned)f2bfu(a0 * id) | ((unsigned)f2bfu(a1 * id) << 16);
        o.y = (unsigned)f2bfu(a2 * id) | ((unsigned)f2bfu(a3 * id) << 16);
        o.z = (unsigned)f2bfu(a4 * id) | ((unsigned)f2bfu(a5 * id) << 16);
        o.w = (unsigned)f2bfu(a6 * id) | ((unsigned)f2bfu(a7 * id) << 16);
        *reinterpret_cast<uint4*>(agg + (size_t)node * HID + fl * 8) = o;
    }
}

// ---------------- combine via MFMA: out = relu(agg @ Wl + bl + h_in @ Wr) ----------------
// h_out may alias agg: each wave reads only its own 16 rows before writing them.
template<int STORE_F32>
__global__ void k_combine_mfma(const bf16* __restrict__ agg, const bf16* __restrict__ h_in,
                               const bf16* __restrict__ WlT, const bf16* __restrict__ WrT,
                               const float* __restrict__ bl, void* __restrict__ outp) {
    const int wid  = threadIdx.x >> 6;
    const int lane = threadIdx.x & 63;
    const int r0   = blockIdx.x * 64 + wid * 16;
    const int lrow = lane & 15;
    const int kgrp = lane >> 4;

    f32x4 acc[8];
#pragma unroll
    for (int c = 0; c < 8; c++) acc[c] = (f32x4){0.f, 0.f, 0.f, 0.f};

    const int arow = min(r0 + lrow, N_NODES - 1);

#pragma unroll
    for (int m = 0; m < 2; m++) {
        const bf16* A  = m ? h_in : agg;
        const bf16* BT = m ? WrT  : WlT;
#pragma unroll
        for (int kk = 0; kk < 4; kk++) {
            const int k0 = kk * 32 + kgrp * 8;
            short8 a = *reinterpret_cast<const short8*>(A + (size_t)arow * HID + k0);
#pragma unroll
            for (int c = 0; c < 8; c++) {
                short8 b = *reinterpret_cast<const short8*>(BT + (size_t)(c * 16 + lrow) * HID + k0);
                acc[c] = __builtin_amdgcn_mfma_f32_16x16x32_bf16(a, b, acc[c], 0, 0, 0);
            }
        }
    }

#pragma unroll
    for (int c = 0; c < 8; c++) {
        const int col = c * 16 + lrow;
        const float bias = bl[col];
#pragma unroll
        for (int r = 0; r < 4; r++) {
            const int row = r0 + kgrp * 4 + r;
            if (row < N_NODES) {
                float v = fmaxf(acc[c][r] + bias, 0.0f);
                if (STORE_F32)
                    ((float*)outp)[(size_t)row * HID + col] = v;
                else
                    ((bf16*)outp)[(size_t)row * HID + col] = __float2bfloat16(v);
            }
        }
    }
}

extern "C" void kernel_launch(void* const* d_in, const int* in_sizes, int n_in,
                              void* d_out, int out_size, void* d_ws, size_t ws_size,
                              hipStream_t stream) {
    const float* x     = (const float*)d_in[0];
    const int*   ei    = (const int*)d_in[1];
    const float* emb_W = (const float*)d_in[2];
    const float* emb_b = (const float*)d_in[3];
    const float* Wl    = (const float*)d_in[4];
    const float* bl    = (const float*)d_in[5];
    const float* Wr    = (const float*)d_in[6];

    const int* src = ei;
    const int* dst = ei + N_EDGES;

    // workspace layout
    char* ws = (char*)d_ws;
    size_t o = 0;
    int*  degbuf = (int*)(ws + o);  o += ((size_t)N_NODES * 4 + 255) & ~(size_t)255;
    int*  rowcur = (int*)(ws + o);  o += ((size_t)N_NODES * 4 + 255) & ~(size_t)255;
    int*  csrsrc = (int*)(ws + o);  o += ((size_t)N_EDGES * 4 + 255) & ~(size_t)255;
    int*  bsum   = (int*)(ws + o);  o += ((size_t)NCH * 4 + 255) & ~(size_t)255;
    int*  boff   = (int*)(ws + o);  o += ((size_t)NCH * 4 + 255) & ~(size_t)255;
    bf16* WlT    = (bf16*)(ws + o); o += ((size_t)NLAYERS * HID * HID * 2 + 255) & ~(size_t)255;
    bf16* WrT    = (bf16*)(ws + o); o += ((size_t)NLAYERS * HID * HID * 2 + 255) & ~(size_t)255;
    bf16* embT   = (bf16*)(ws + o); o += ((size_t)HID * KPAD * 2 + 255) & ~(size_t)255;
    float* qs    = (float*)(ws + o);o += ((size_t)N_NODES * 4 + 255) & ~(size_t)255;
    unsigned char* q8 = (unsigned char*)(ws + o); o += ((size_t)N_NODES * HID + 255) & ~(size_t)255;
    bf16* bufA   = (bf16*)(ws + o); o += ((size_t)N_NODES * HID * 2 + 255) & ~(size_t)255;
    bf16* bufB   = (bf16*)(ws + o);

    // ---- build CSR ----
    hipMemsetAsync(degbuf, 0, (size_t)N_NODES * sizeof(int), stream);
    k_deg<<<(N_EDGES + 255) / 256, 256, 0, stream>>>(dst, degbuf);
    k_scan1<<<NCH, SB, 0, stream>>>(degbuf, bsum);
    k_scan2<<<1, SB, 0, stream>>>(bsum, boff);
    k_scan3<<<NCH, SB, 0, stream>>>(degbuf, boff, rowcur);
    k_invdeg<<<(N_NODES + 255) / 256, 256, 0, stream>>>(degbuf);
    const float* invdeg = (const float*)degbuf;
    k_fill<<<(N_EDGES + 255) / 256, 256, 0, stream>>>(src, dst, rowcur, csrsrc);
    // rowcur[n] is now the END offset of row n

    // ---- weight prep ----
    k_wconv<<<(NLAYERS * HID * HID + 255) / 256, 256, 0, stream>>>(Wl, Wr, WlT, WrT);
    k_wembT<<<(HID * KPAD + 255) / 256, 256, 0, stream>>>(emb_W, embT);

    // ---- h0 = relu(x @ emb_W + emb_b) -> bufA (bf16), via MFMA ----
    const int cgrid = (N_NODES + 63) / 64;   // 782
    const int ngrid = (N_NODES + 3) / 4;     // 12500 (1 wave/node kernels)
    k_embed_mfma<<<cgrid, 256, 0, stream>>>(x, embT, emb_b, bufA);

    for (int l = 0; l < NLAYERS; l++) {
        bf16* h_in = (l & 1) ? bufB : bufA;
        bf16* aggb = (l & 1) ? bufA : bufB;
        k_quant<<<ngrid, 256, 0, stream>>>(h_in, q8, qs);
        k_gather<<<ngrid, 256, 0, stream>>>(rowcur, csrsrc, q8, qs, invdeg, aggb);
        const bf16* wlt = WlT + (size_t)l * HID * HID;
        const bf16* wrt = WrT + (size_t)l * HID * HID;
        const float* blp = bl + (size_t)l * HID;
        if (l == NLAYERS - 1)
            k_combine_mfma<1><<<cgrid, 256, 0, stream>>>(aggb, h_in, wlt, wrt, blp, d_out);
        else
            k_combine_mfma<0><<<cgrid, 256, 0, stream>>>(aggb, h_in, wlt, wrt, blp, aggb);
    }
}

// Round 11
// 285.547 us; speedup vs baseline: 1.4900x; 1.4900x over previous
//
#include <hip/hip_runtime.h>
#include <hip/hip_bf16.h>

#define N_NODES 50000
#define N_EDGES 625000
#define IN_DIM  300
#define KPAD    320   // IN_DIM padded to multiple of 32
#define HID     128
#define NLAYERS 4

#define SB      256                            // scan block size
#define NCH     ((N_NODES + SB - 1) / SB)      // 196 chunks

typedef __hip_bfloat16 bf16;
typedef __attribute__((ext_vector_type(8))) short short8;   // 8 bf16 = 4 VGPRs
typedef __attribute__((ext_vector_type(4))) float f32x4;

__device__ inline short f2bf(float v) {
    bf16 t = __float2bfloat16(v);
    return *reinterpret_cast<short*>(&t);
}
__device__ inline unsigned short f2bfu(float v) {
    bf16 t = __float2bfloat16(v);
    return *reinterpret_cast<unsigned short*>(&t);
}
__device__ inline float bflo(unsigned v) { return __uint_as_float((v & 0xffffu) << 16); }
__device__ inline float bfhi(unsigned v) { return __uint_as_float(v & 0xffff0000u); }

// ---------------- degree histogram (int) ----------------
__global__ void k_deg(const int* __restrict__ dst, int* __restrict__ deg) {
    int e = blockIdx.x * blockDim.x + threadIdx.x;
    if (e < N_EDGES) atomicAdd(&deg[dst[e]], 1);
}

// ---------------- hierarchical scan: deg -> exclusive prefix ----------------
__global__ void k_scan1(const int* __restrict__ deg, int* __restrict__ bsum) {
    const int i = blockIdx.x * SB + threadIdx.x;
    int v = (i < N_NODES) ? deg[i] : 0;
#pragma unroll
    for (int off = 32; off > 0; off >>= 1) v += __shfl_down(v, off);
    __shared__ int wsum[SB / 64];
    if ((threadIdx.x & 63) == 0) wsum[threadIdx.x >> 6] = v;
    __syncthreads();
    if (threadIdx.x == 0) {
        int s = 0;
#pragma unroll
        for (int w = 0; w < SB / 64; w++) s += wsum[w];
        bsum[blockIdx.x] = s;
    }
}

__global__ void k_scan2(const int* __restrict__ bsum, int* __restrict__ boff) {
    __shared__ int s[SB];
    const int t = threadIdx.x;
    int v = (t < NCH) ? bsum[t] : 0;
    s[t] = v;
    __syncthreads();
    for (int off = 1; off < SB; off <<= 1) {
        int u = (t >= off) ? s[t - off] : 0;
        __syncthreads();
        s[t] += u;
        __syncthreads();
    }
    if (t < NCH) boff[t] = s[t] - v;   // exclusive
}

// scan3: within-chunk scan + chunk offset; ALSO converts deg -> invdeg in place
__global__ void k_scan3(int* __restrict__ degbuf, const int* __restrict__ boff,
                        int* __restrict__ rowcur) {
    __shared__ int s[SB];
    const int b = blockIdx.x, t = threadIdx.x;
    const int i = b * SB + t;
    int v = (i < N_NODES) ? degbuf[i] : 0;
    s[t] = v;
    __syncthreads();
    for (int off = 1; off < SB; off <<= 1) {
        int u = (t >= off) ? s[t - off] : 0;
        __syncthreads();
        s[t] += u;
        __syncthreads();
    }
    if (i < N_NODES) {
        rowcur[i] = boff[b] + s[t] - v;   // exclusive prefix
        ((float*)degbuf)[i] = 1.0f / (float)max(v, 1);   // invdeg, in place
    }
}

// ---------------- CSR fill ----------------
__global__ void k_fill(const int* __restrict__ src, const int* __restrict__ dst,
                       int* __restrict__ rowcur, int* __restrict__ csr_src) {
    int e = blockIdx.x * blockDim.x + threadIdx.x;
    if (e < N_EDGES) {
        int d = dst[e];
        int pos = atomicAdd(&rowcur[d], 1);
        csr_src[pos] = src[e];
    }
}

// ---------------- Wl/Wr -> W^T bf16 ----------------
__global__ void k_wconv(const float* __restrict__ Wl, const float* __restrict__ Wr,
                        bf16* __restrict__ WlT, bf16* __restrict__ WrT) {
    int idx = blockIdx.x * 256 + threadIdx.x;
    if (idx >= NLAYERS * HID * HID) return;
    int l = idx / (HID * HID);
    int rem = idx - l * HID * HID;
    int k = rem >> 7;
    int f = rem & 127;
    size_t o = (size_t)l * HID * HID + (size_t)f * HID + k;
    WlT[o] = __float2bfloat16(Wl[idx]);
    WrT[o] = __float2bfloat16(Wr[idx]);
}

// ---------------- emb_W[300][128] -> embT[128][KPAD] bf16 (zero-padded K) ----------------
__global__ void k_wembT(const float* __restrict__ W, bf16* __restrict__ embT) {
    int idx = blockIdx.x * 256 + threadIdx.x;
    if (idx >= HID * KPAD) return;
    int f = idx / KPAD, k = idx - f * KPAD;
    float v = (k < IN_DIM) ? W[(size_t)k * HID + f] : 0.0f;
    embT[idx] = __float2bfloat16(v);
}

// ---------------- embedding via MFMA (round-6 version, measured ~53 us) ----------------
__global__ void k_embed_mfma(const float* __restrict__ x, const bf16* __restrict__ embT,
                             const float* __restrict__ b, bf16* __restrict__ h) {
    const int wid  = threadIdx.x >> 6;
    const int lane = threadIdx.x & 63;
    const int r0   = blockIdx.x * 64 + wid * 16;
    const int lrow = lane & 15;
    const int kgrp = lane >> 4;

    const int arow = min(r0 + lrow, N_NODES - 1);
    const float* xrow = x + (size_t)arow * IN_DIM;

    f32x4 acc[8];
#pragma unroll
    for (int c = 0; c < 8; c++) acc[c] = (f32x4){0.f, 0.f, 0.f, 0.f};

    for (int kk = 0; kk < KPAD / 32; kk++) {
        const int k0 = kk * 32 + kgrp * 8;
        short8 a;
        if (kk < 9) {
            float4 f0 = *reinterpret_cast<const float4*>(xrow + k0);
            float4 f1 = *reinterpret_cast<const float4*>(xrow + k0 + 4);
            a[0] = f2bf(f0.x); a[1] = f2bf(f0.y); a[2] = f2bf(f0.z); a[3] = f2bf(f0.w);
            a[4] = f2bf(f1.x); a[5] = f2bf(f1.y); a[6] = f2bf(f1.z); a[7] = f2bf(f1.w);
        } else {
#pragma unroll
            for (int j = 0; j < 8; j++) {
                int k = k0 + j;
                a[j] = f2bf((k < IN_DIM) ? xrow[k] : 0.0f);
            }
        }
#pragma unroll
        for (int c = 0; c < 8; c++) {
            short8 bfrag = *reinterpret_cast<const short8*>(embT + (size_t)(c * 16 + lrow) * KPAD + k0);
            acc[c] = __builtin_amdgcn_mfma_f32_16x16x32_bf16(a, bfrag, acc[c], 0, 0, 0);
        }
    }

#pragma unroll
    for (int c = 0; c < 8; c++) {
        const int col = c * 16 + lrow;
        const float bias = b[col];
#pragma unroll
        for (int r = 0; r < 4; r++) {
            const int row = r0 + kgrp * 4 + r;
            if (row < N_NODES)
                h[(size_t)row * HID + col] = __float2bfloat16(fmaxf(acc[c][r] + bias, 0.0f));
        }
    }
}

// ---------------- gather-aggregate: quarter-wave per edge, 16B/lane, 4-deep ----------------
__global__ void k_gather(const int* __restrict__ rowend, const int* __restrict__ csr_src,
                         const bf16* __restrict__ h, const float* __restrict__ invdeg,
                         bf16* __restrict__ agg) {
    const int node = blockIdx.x * (blockDim.x >> 6) + (threadIdx.x >> 6);
    if (node >= N_NODES) return;
    const int lane = threadIdx.x & 63;
    const int g    = lane >> 4;
    const int fl   = lane & 15;
    const int beg = (node == 0) ? 0 : rowend[node - 1];
    const int end = rowend[node];

    float a0 = 0.f, a1 = 0.f, a2 = 0.f, a3 = 0.f;
    float a4 = 0.f, a5 = 0.f, a6 = 0.f, a7 = 0.f;
    float c0 = 0.f, c1 = 0.f, c2 = 0.f, c3 = 0.f;
    float c4 = 0.f, c5 = 0.f, c6 = 0.f, c7 = 0.f;

    int e = beg;
    for (; e + 16 <= end; e += 16) {        // 16 edges in flight per wave
        int s0 = csr_src[e + g];
        int s1 = csr_src[e + 4 + g];
        int s2 = csr_src[e + 8 + g];
        int s3 = csr_src[e + 12 + g];
        uint4 v0 = *reinterpret_cast<const uint4*>(h + (size_t)s0 * HID + fl * 8);
        uint4 v1 = *reinterpret_cast<const uint4*>(h + (size_t)s1 * HID + fl * 8);
        uint4 v2 = *reinterpret_cast<const uint4*>(h + (size_t)s2 * HID + fl * 8);
        uint4 v3 = *reinterpret_cast<const uint4*>(h + (size_t)s3 * HID + fl * 8);
        a0 += bflo(v0.x); a1 += bfhi(v0.x); a2 += bflo(v0.y); a3 += bfhi(v0.y);
        a4 += bflo(v0.z); a5 += bfhi(v0.z); a6 += bflo(v0.w); a7 += bfhi(v0.w);
        c0 += bflo(v1.x); c1 += bfhi(v1.x); c2 += bflo(v1.y); c3 += bfhi(v1.y);
        c4 += bflo(v1.z); c5 += bfhi(v1.z); c6 += bflo(v1.w); c7 += bfhi(v1.w);
        a0 += bflo(v2.x); a1 += bfhi(v2.x); a2 += bflo(v2.y); a3 += bfhi(v2.y);
        a4 += bflo(v2.z); a5 += bfhi(v2.z); a6 += bflo(v2.w); a7 += bfhi(v2.w);
        c0 += bflo(v3.x); c1 += bfhi(v3.x); c2 += bflo(v3.y); c3 += bfhi(v3.y);
        c4 += bflo(v3.z); c5 += bfhi(v3.z); c6 += bflo(v3.w); c7 += bfhi(v3.w);
    }
    for (; e + 8 <= end; e += 8) {
        int s0 = csr_src[e + g];
        int s1 = csr_src[e + 4 + g];
        uint4 v0 = *reinterpret_cast<const uint4*>(h + (size_t)s0 * HID + fl * 8);
        uint4 v1 = *reinterpret_cast<const uint4*>(h + (size_t)s1 * HID + fl * 8);
        a0 += bflo(v0.x); a1 += bfhi(v0.x); a2 += bflo(v0.y); a3 += bfhi(v0.y);
        a4 += bflo(v0.z); a5 += bfhi(v0.z); a6 += bflo(v0.w); a7 += bfhi(v0.w);
        c0 += bflo(v1.x); c1 += bfhi(v1.x); c2 += bflo(v1.y); c3 += bfhi(v1.y);
        c4 += bflo(v1.z); c5 += bfhi(v1.z); c6 += bflo(v1.w); c7 += bfhi(v1.w);
    }
    for (; e + 4 <= end; e += 4) {
        int s0 = csr_src[e + g];
        uint4 v0 = *reinterpret_cast<const uint4*>(h + (size_t)s0 * HID + fl * 8);
        a0 += bflo(v0.x); a1 += bfhi(v0.x); a2 += bflo(v0.y); a3 += bfhi(v0.y);
        a4 += bflo(v0.z); a5 += bfhi(v0.z); a6 += bflo(v0.w); a7 += bfhi(v0.w);
    }
    if (e < end) {                           // tail: 1..3 edges, per-group predicated
        int idx = e + g;
        bool valid = idx < end;
        int s = csr_src[valid ? idx : end - 1];
        uint4 v = *reinterpret_cast<const uint4*>(h + (size_t)s * HID + fl * 8);
        if (valid) {
            a0 += bflo(v.x); a1 += bfhi(v.x); a2 += bflo(v.y); a3 += bfhi(v.y);
            a4 += bflo(v.z); a5 += bfhi(v.z); a6 += bflo(v.w); a7 += bfhi(v.w);
        }
    }
    a0 += c0; a1 += c1; a2 += c2; a3 += c3;
    a4 += c4; a5 += c5; a6 += c6; a7 += c7;

    // reduce across the 4 groups (lanes differing in bits 4,5)
    a0 += __shfl_xor(a0, 16); a1 += __shfl_xor(a1, 16);
    a2 += __shfl_xor(a2, 16); a3 += __shfl_xor(a3, 16);
    a4 += __shfl_xor(a4, 16); a5 += __shfl_xor(a5, 16);
    a6 += __shfl_xor(a6, 16); a7 += __shfl_xor(a7, 16);
    a0 += __shfl_xor(a0, 32); a1 += __shfl_xor(a1, 32);
    a2 += __shfl_xor(a2, 32); a3 += __shfl_xor(a3, 32);
    a4 += __shfl_xor(a4, 32); a5 += __shfl_xor(a5, 32);
    a6 += __shfl_xor(a6, 32); a7 += __shfl_xor(a7, 32);

    if (g == 0) {
        const float id = invdeg[node];
        uint4 o;
        o.x = (unsigned)f2bfu(a0 * id) | ((unsigned)f2bfu(a1 * id) << 16);
        o.y = (unsigned)f2bfu(a2 * id) | ((unsigned)f2bfu(a3 * id) << 16);
        o.z = (unsigned)f2bfu(a4 * id) | ((unsigned)f2bfu(a5 * id) << 16);
        o.w = (unsigned)f2bfu(a6 * id) | ((unsigned)f2bfu(a7 * id) << 16);
        *reinterpret_cast<uint4*>(agg + (size_t)node * HID + fl * 8) = o;
    }
}

// ---------------- combine via MFMA with LDS-staged weights ----------------
// out = relu(agg @ Wl + bl + h_in @ Wr). 512 thr = 8 waves x 16 rows = 128 rows/block.
// Wl^T/Wr^T staged in LDS (32 KB each) with 16B-chunk XOR swizzle: chunk' = chunk ^ (row&7)
// -> B-fragment ds_read_b128 is bank-uniform (conflict-free).
// h_out may alias agg: each wave reads only its own 16 rows before writing them.
template<int STORE_F32>
__global__ __launch_bounds__(512)
void k_combine_mfma(const bf16* __restrict__ agg, const bf16* __restrict__ h_in,
                    const bf16* __restrict__ WlT, const bf16* __restrict__ WrT,
                    const float* __restrict__ bl, void* __restrict__ outp) {
    __shared__ bf16 wl_s[HID][HID];   // 32 KB, swizzled chunks
    __shared__ bf16 wr_s[HID][HID];   // 32 KB
    const int wid  = threadIdx.x >> 6;          // 0..7
    const int lane = threadIdx.x & 63;
    const int r0   = blockIdx.x * 128 + wid * 16;
    const int lrow = lane & 15;
    const int kgrp = lane >> 4;

    // stage weights: 128 rows x 16 chunks of 16B, coalesced reads, swizzled LDS writes
    for (int id = threadIdx.x; id < HID * 16; id += 512) {
        const int row = id >> 4, c16 = id & 15;
        const int sc  = c16 ^ (row & 7);
        *reinterpret_cast<uint4*>(&wl_s[row][sc * 8]) =
            *reinterpret_cast<const uint4*>(WlT + (size_t)row * HID + c16 * 8);
        *reinterpret_cast<uint4*>(&wr_s[row][sc * 8]) =
            *reinterpret_cast<const uint4*>(WrT + (size_t)row * HID + c16 * 8);
    }
    __syncthreads();

    f32x4 acc[8];
#pragma unroll
    for (int c = 0; c < 8; c++) acc[c] = (f32x4){0.f, 0.f, 0.f, 0.f};

    const int arow = min(r0 + lrow, N_NODES - 1);

    // m = 0: A = agg, B = wl_s
#pragma unroll
    for (int kk = 0; kk < 4; kk++) {
        const int k0 = kk * 32 + kgrp * 8;
        short8 a = *reinterpret_cast<const short8*>(agg + (size_t)arow * HID + k0);
#pragma unroll
        for (int c = 0; c < 8; c++) {
            const int row = c * 16 + lrow;
            const int kc  = (kk * 4 + kgrp) ^ (lrow & 7);
            short8 b = *reinterpret_cast<const short8*>(&wl_s[row][kc * 8]);
            acc[c] = __builtin_amdgcn_mfma_f32_16x16x32_bf16(a, b, acc[c], 0, 0, 0);
        }
    }
    // m = 1: A = h_in, B = wr_s
#pragma unroll
    for (int kk = 0; kk < 4; kk++) {
        const int k0 = kk * 32 + kgrp * 8;
        short8 a = *reinterpret_cast<const short8*>(h_in + (size_t)arow * HID + k0);
#pragma unroll
        for (int c = 0; c < 8; c++) {
            const int row = c * 16 + lrow;
            const int kc  = (kk * 4 + kgrp) ^ (lrow & 7);
            short8 b = *reinterpret_cast<const short8*>(&wr_s[row][kc * 8]);
            acc[c] = __builtin_amdgcn_mfma_f32_16x16x32_bf16(a, b, acc[c], 0, 0, 0);
        }
    }

#pragma unroll
    for (int c = 0; c < 8; c++) {
        const int col = c * 16 + lrow;
        const float bias = bl[col];
#pragma unroll
        for (int r = 0; r < 4; r++) {
            const int row = r0 + kgrp * 4 + r;
            if (row < N_NODES) {
                float v = fmaxf(acc[c][r] + bias, 0.0f);
                if (STORE_F32)
                    ((float*)outp)[(size_t)row * HID + col] = v;
                else
                    ((bf16*)outp)[(size_t)row * HID + col] = __float2bfloat16(v);
            }
        }
    }
}

extern "C" void kernel_launch(void* const* d_in, const int* in_sizes, int n_in,
                              void* d_out, int out_size, void* d_ws, size_t ws_size,
                              hipStream_t stream) {
    const float* x     = (const float*)d_in[0];
    const int*   ei    = (const int*)d_in[1];
    const float* emb_W = (const float*)d_in[2];
    const float* emb_b = (const float*)d_in[3];
    const float* Wl    = (const float*)d_in[4];
    const float* bl    = (const float*)d_in[5];
    const float* Wr    = (const float*)d_in[6];

    const int* src = ei;
    const int* dst = ei + N_EDGES;

    // workspace layout
    char* ws = (char*)d_ws;
    size_t o = 0;
    int*  degbuf = (int*)(ws + o);  o += ((size_t)N_NODES * 4 + 255) & ~(size_t)255;
    int*  rowcur = (int*)(ws + o);  o += ((size_t)N_NODES * 4 + 255) & ~(size_t)255;
    int*  csrsrc = (int*)(ws + o);  o += ((size_t)N_EDGES * 4 + 255) & ~(size_t)255;
    int*  bsum   = (int*)(ws + o);  o += ((size_t)NCH * 4 + 255) & ~(size_t)255;
    int*  boff   = (int*)(ws + o);  o += ((size_t)NCH * 4 + 255) & ~(size_t)255;
    bf16* WlT    = (bf16*)(ws + o); o += ((size_t)NLAYERS * HID * HID * 2 + 255) & ~(size_t)255;
    bf16* WrT    = (bf16*)(ws + o); o += ((size_t)NLAYERS * HID * HID * 2 + 255) & ~(size_t)255;
    bf16* embT   = (bf16*)(ws + o); o += ((size_t)HID * KPAD * 2 + 255) & ~(size_t)255;
    bf16* bufA   = (bf16*)(ws + o); o += ((size_t)N_NODES * HID * 2 + 255) & ~(size_t)255;
    bf16* bufB   = (bf16*)(ws + o);

    // ---- build CSR (invdeg fused into scan3) ----
    hipMemsetAsync(degbuf, 0, (size_t)N_NODES * sizeof(int), stream);
    k_deg<<<(N_EDGES + 255) / 256, 256, 0, stream>>>(dst, degbuf);
    k_scan1<<<NCH, SB, 0, stream>>>(degbuf, bsum);
    k_scan2<<<1, SB, 0, stream>>>(bsum, boff);
    k_scan3<<<NCH, SB, 0, stream>>>(degbuf, boff, rowcur);
    const float* invdeg = (const float*)degbuf;
    k_fill<<<(N_EDGES + 255) / 256, 256, 0, stream>>>(src, dst, rowcur, csrsrc);
    // rowcur[n] is now the END offset of row n

    // ---- weight prep ----
    k_wconv<<<(NLAYERS * HID * HID + 255) / 256, 256, 0, stream>>>(Wl, Wr, WlT, WrT);
    k_wembT<<<(HID * KPAD + 255) / 256, 256, 0, stream>>>(emb_W, embT);

    // ---- h0 = relu(x @ emb_W + emb_b) -> bufA (bf16), via MFMA ----
    const int egrid = (N_NODES + 63) / 64;    // 782
    const int ngrid = (N_NODES + 3) / 4;      // 12500
    const int cgrid = (N_NODES + 127) / 128;  // 391
    k_embed_mfma<<<egrid, 256, 0, stream>>>(x, embT, emb_b, bufA);

    for (int l = 0; l < NLAYERS; l++) {
        bf16* h_in = (l & 1) ? bufB : bufA;
        bf16* aggb = (l & 1) ? bufA : bufB;
        k_gather<<<ngrid, 256, 0, stream>>>(rowcur, csrsrc, h_in, invdeg, aggb);
        const bf16* wlt = WlT + (size_t)l * HID * HID;
        const bf16* wrt = WrT + (size_t)l * HID * HID;
        const float* blp = bl + (size_t)l * HID;
        if (l == NLAYERS - 1)
            k_combine_mfma<1><<<cgrid, 512, 0, stream>>>(aggb, h_in, wlt, wrt, blp, d_out);
        else
            k_combine_mfma<0><<<cgrid, 512, 0, stream>>>(aggb, h_in, wlt, wrt, blp, aggb);
    }
}

// Round 12
// 260.638 us; speedup vs baseline: 1.6324x; 1.0956x over previous
//
#include <hip/hip_runtime.h>
#include <hip/hip_bf16.h>

#define N_NODES 50000
#define N_EDGES 625000
#define IN_DIM  300
#define KPAD    320   // IN_DIM padded to multiple of 32
#define HID     128
#define NLAYERS 4

#define SB      256                            // scan block size
#define NCH     ((N_NODES + SB - 1) / SB)      // 196 chunks

typedef __hip_bfloat16 bf16;
typedef __attribute__((ext_vector_type(8))) short short8;   // 8 bf16 = 4 VGPRs
typedef __attribute__((ext_vector_type(4))) float f32x4;

__device__ inline short f2bf(float v) {
    bf16 t = __float2bfloat16(v);
    return *reinterpret_cast<short*>(&t);
}
__device__ inline unsigned short f2bfu(float v) {
    bf16 t = __float2bfloat16(v);
    return *reinterpret_cast<unsigned short*>(&t);
}
__device__ inline float bflo(unsigned v) { return __uint_as_float((v & 0xffffu) << 16); }
__device__ inline float bfhi(unsigned v) { return __uint_as_float(v & 0xffff0000u); }

// ---------------- degree histogram (int) ----------------
__global__ void k_deg(const int* __restrict__ dst, int* __restrict__ deg) {
    int e = blockIdx.x * blockDim.x + threadIdx.x;
    if (e < N_EDGES) atomicAdd(&deg[dst[e]], 1);
}

// ---------------- scan1: per-chunk sums ----------------
__global__ void k_scan1(const int* __restrict__ deg, int* __restrict__ bsum) {
    const int i = blockIdx.x * SB + threadIdx.x;
    int v = (i < N_NODES) ? deg[i] : 0;
#pragma unroll
    for (int off = 32; off > 0; off >>= 1) v += __shfl_down(v, off);
    __shared__ int wsum[SB / 64];
    if ((threadIdx.x & 63) == 0) wsum[threadIdx.x >> 6] = v;
    __syncthreads();
    if (threadIdx.x == 0) {
        int s = 0;
#pragma unroll
        for (int w = 0; w < SB / 64; w++) s += wsum[w];
        bsum[blockIdx.x] = s;
    }
}

// scan3: block-offset scan (inlined, replaces scan2) + within-chunk scan;
// ALSO converts deg -> invdeg in place.
__global__ void k_scan3(int* __restrict__ degbuf, const int* __restrict__ bsum,
                        int* __restrict__ rowcur) {
    __shared__ int s[SB];
    __shared__ int bs[SB];
    const int b = blockIdx.x, t = threadIdx.x;

    // exclusive offset of this block, computed locally from bsum (NCH <= SB)
    int bv = (t < NCH) ? bsum[t] : 0;
    bs[t] = bv;
    __syncthreads();
    for (int off = 1; off < SB; off <<= 1) {
        int u = (t >= off) ? bs[t - off] : 0;
        __syncthreads();
        bs[t] += u;
        __syncthreads();
    }
    const int boff = (b == 0) ? 0 : bs[b - 1];

    const int i = b * SB + t;
    int v = (i < N_NODES) ? degbuf[i] : 0;
    s[t] = v;
    __syncthreads();
    for (int off = 1; off < SB; off <<= 1) {
        int u = (t >= off) ? s[t - off] : 0;
        __syncthreads();
        s[t] += u;
        __syncthreads();
    }
    if (i < N_NODES) {
        rowcur[i] = boff + s[t] - v;                     // exclusive prefix
        ((float*)degbuf)[i] = 1.0f / (float)max(v, 1);   // invdeg, in place
    }
}

// ---------------- CSR fill ----------------
__global__ void k_fill(const int* __restrict__ src, const int* __restrict__ dst,
                       int* __restrict__ rowcur, int* __restrict__ csr_src) {
    int e = blockIdx.x * blockDim.x + threadIdx.x;
    if (e < N_EDGES) {
        int d = dst[e];
        int pos = atomicAdd(&rowcur[d], 1);
        csr_src[pos] = src[e];
    }
}

// ---------------- weight prep: Wl/Wr -> W^T bf16, emb_W -> embT (fused) ----------------
__global__ void k_wprep(const float* __restrict__ Wl, const float* __restrict__ Wr,
                        const float* __restrict__ embW,
                        bf16* __restrict__ WlT, bf16* __restrict__ WrT,
                        bf16* __restrict__ embT) {
    int idx = blockIdx.x * 256 + threadIdx.x;
    const int total1 = NLAYERS * HID * HID;
    if (idx < total1) {
        int l = idx / (HID * HID);
        int rem = idx - l * HID * HID;
        int k = rem >> 7;
        int f = rem & 127;
        size_t o = (size_t)l * HID * HID + (size_t)f * HID + k;
        WlT[o] = __float2bfloat16(Wl[idx]);
        WrT[o] = __float2bfloat16(Wr[idx]);
        return;
    }
    int idx2 = idx - total1;
    if (idx2 < HID * KPAD) {
        int f = idx2 / KPAD, k = idx2 - f * KPAD;
        float v = (k < IN_DIM) ? embW[(size_t)k * HID + f] : 0.0f;
        embT[idx2] = __float2bfloat16(v);
    }
}

// ---------------- embedding via MFMA with LDS-staged embT (k < 256) ----------------
// 512 thr = 8 waves x 16 rows = 128 rows/block; grid 391; 64 KB LDS -> 2 blocks/CU.
// LDS swizzle: 16B chunk' = chunk ^ (row & 7)  (32 chunks/row, closed under XOR).
__global__ __launch_bounds__(512)
void k_embed_mfma(const float* __restrict__ x, const bf16* __restrict__ embT,
                  const float* __restrict__ b, bf16* __restrict__ h) {
    __shared__ bf16 emb_s[HID][256];   // 64 KB
    const int wid  = threadIdx.x >> 6;          // 0..7
    const int lane = threadIdx.x & 63;
    const int r0   = blockIdx.x * 128 + wid * 16;
    const int lrow = lane & 15;
    const int kgrp = lane >> 4;

    // stage embT rows (k < 256): 128 rows x 32 chunks of 16 B
    for (int id = threadIdx.x; id < HID * 32; id += 512) {
        const int row = id >> 5, ch = id & 31;
        const int sc  = ch ^ (row & 7);
        *reinterpret_cast<uint4*>(&emb_s[row][sc * 8]) =
            *reinterpret_cast<const uint4*>(embT + (size_t)row * KPAD + ch * 8);
    }
    __syncthreads();

    const int arow = min(r0 + lrow, N_NODES - 1);
    const float* xrow = x + (size_t)arow * IN_DIM;

    f32x4 acc[8];
#pragma unroll
    for (int c = 0; c < 8; c++) acc[c] = (f32x4){0.f, 0.f, 0.f, 0.f};

#pragma unroll
    for (int kk = 0; kk < 8; kk++) {            // k < 256: B from LDS
        const int k0 = kk * 32 + kgrp * 8;
        float4 f0 = *reinterpret_cast<const float4*>(xrow + k0);
        float4 f1 = *reinterpret_cast<const float4*>(xrow + k0 + 4);
        short8 a;
        a[0] = f2bf(f0.x); a[1] = f2bf(f0.y); a[2] = f2bf(f0.z); a[3] = f2bf(f0.w);
        a[4] = f2bf(f1.x); a[5] = f2bf(f1.y); a[6] = f2bf(f1.z); a[7] = f2bf(f1.w);
#pragma unroll
        for (int c = 0; c < 8; c++) {
            const int row = c * 16 + lrow;
            const int kc  = (kk * 4 + kgrp) ^ (row & 7);
            short8 bfrag = *reinterpret_cast<const short8*>(&emb_s[row][kc * 8]);
            acc[c] = __builtin_amdgcn_mfma_f32_16x16x32_bf16(a, bfrag, acc[c], 0, 0, 0);
        }
    }
    {   // kk = 8: k in [256,288), all valid; B from global
        const int k0 = 256 + kgrp * 8;
        float4 f0 = *reinterpret_cast<const float4*>(xrow + k0);
        float4 f1 = *reinterpret_cast<const float4*>(xrow + k0 + 4);
        short8 a;
        a[0] = f2bf(f0.x); a[1] = f2bf(f0.y); a[2] = f2bf(f0.z); a[3] = f2bf(f0.w);
        a[4] = f2bf(f1.x); a[5] = f2bf(f1.y); a[6] = f2bf(f1.z); a[7] = f2bf(f1.w);
#pragma unroll
        for (int c = 0; c < 8; c++) {
            short8 bfrag = *reinterpret_cast<const short8*>(embT + (size_t)(c * 16 + lrow) * KPAD + k0);
            acc[c] = __builtin_amdgcn_mfma_f32_16x16x32_bf16(a, bfrag, acc[c], 0, 0, 0);
        }
    }
    {   // kk = 9: k in [288,320), mask k >= 300; B from global (zero-padded)
        const int k0 = 288 + kgrp * 8;
        short8 a;
#pragma unroll
        for (int j = 0; j < 8; j++) {
            int k = k0 + j;
            a[j] = f2bf((k < IN_DIM) ? xrow[k] : 0.0f);
        }
#pragma unroll
        for (int c = 0; c < 8; c++) {
            short8 bfrag = *reinterpret_cast<const short8*>(embT + (size_t)(c * 16 + lrow) * KPAD + k0);
            acc[c] = __builtin_amdgcn_mfma_f32_16x16x32_bf16(a, bfrag, acc[c], 0, 0, 0);
        }
    }

#pragma unroll
    for (int c = 0; c < 8; c++) {
        const int col = c * 16 + lrow;
        const float bias = b[col];
#pragma unroll
        for (int r = 0; r < 4; r++) {
            const int row = r0 + kgrp * 4 + r;
            if (row < N_NODES)
                h[(size_t)row * HID + col] = __float2bfloat16(fmaxf(acc[c][r] + bias, 0.0f));
        }
    }
}

// ---------------- gather-aggregate: quarter-wave per edge, 16B/lane, 4-deep ----------------
__global__ void k_gather(const int* __restrict__ rowend, const int* __restrict__ csr_src,
                         const bf16* __restrict__ h, const float* __restrict__ invdeg,
                         bf16* __restrict__ agg) {
    const int node = blockIdx.x * (blockDim.x >> 6) + (threadIdx.x >> 6);
    if (node >= N_NODES) return;
    const int lane = threadIdx.x & 63;
    const int g    = lane >> 4;
    const int fl   = lane & 15;
    const int beg = (node == 0) ? 0 : rowend[node - 1];
    const int end = rowend[node];

    float a0 = 0.f, a1 = 0.f, a2 = 0.f, a3 = 0.f;
    float a4 = 0.f, a5 = 0.f, a6 = 0.f, a7 = 0.f;
    float c0 = 0.f, c1 = 0.f, c2 = 0.f, c3 = 0.f;
    float c4 = 0.f, c5 = 0.f, c6 = 0.f, c7 = 0.f;

    int e = beg;
    for (; e + 16 <= end; e += 16) {        // 16 edges in flight per wave
        int s0 = csr_src[e + g];
        int s1 = csr_src[e + 4 + g];
        int s2 = csr_src[e + 8 + g];
        int s3 = csr_src[e + 12 + g];
        uint4 v0 = *reinterpret_cast<const uint4*>(h + (size_t)s0 * HID + fl * 8);
        uint4 v1 = *reinterpret_cast<const uint4*>(h + (size_t)s1 * HID + fl * 8);
        uint4 v2 = *reinterpret_cast<const uint4*>(h + (size_t)s2 * HID + fl * 8);
        uint4 v3 = *reinterpret_cast<const uint4*>(h + (size_t)s3 * HID + fl * 8);
        a0 += bflo(v0.x); a1 += bfhi(v0.x); a2 += bflo(v0.y); a3 += bfhi(v0.y);
        a4 += bflo(v0.z); a5 += bfhi(v0.z); a6 += bflo(v0.w); a7 += bfhi(v0.w);
        c0 += bflo(v1.x); c1 += bfhi(v1.x); c2 += bflo(v1.y); c3 += bfhi(v1.y);
        c4 += bflo(v1.z); c5 += bfhi(v1.z); c6 += bflo(v1.w); c7 += bfhi(v1.w);
        a0 += bflo(v2.x); a1 += bfhi(v2.x); a2 += bflo(v2.y); a3 += bfhi(v2.y);
        a4 += bflo(v2.z); a5 += bfhi(v2.z); a6 += bflo(v2.w); a7 += bfhi(v2.w);
        c0 += bflo(v3.x); c1 += bfhi(v3.x); c2 += bflo(v3.y); c3 += bfhi(v3.y);
        c4 += bflo(v3.z); c5 += bfhi(v3.z); c6 += bflo(v3.w); c7 += bfhi(v3.w);
    }
    for (; e + 8 <= end; e += 8) {
        int s0 = csr_src[e + g];
        int s1 = csr_src[e + 4 + g];
        uint4 v0 = *reinterpret_cast<const uint4*>(h + (size_t)s0 * HID + fl * 8);
        uint4 v1 = *reinterpret_cast<const uint4*>(h + (size_t)s1 * HID + fl * 8);
        a0 += bflo(v0.x); a1 += bfhi(v0.x); a2 += bflo(v0.y); a3 += bfhi(v0.y);
        a4 += bflo(v0.z); a5 += bfhi(v0.z); a6 += bflo(v0.w); a7 += bfhi(v0.w);
        c0 += bflo(v1.x); c1 += bfhi(v1.x); c2 += bflo(v1.y); c3 += bfhi(v1.y);
        c4 += bflo(v1.z); c5 += bfhi(v1.z); c6 += bflo(v1.w); c7 += bfhi(v1.w);
    }
    for (; e + 4 <= end; e += 4) {
        int s0 = csr_src[e + g];
        uint4 v0 = *reinterpret_cast<const uint4*>(h + (size_t)s0 * HID + fl * 8);
        a0 += bflo(v0.x); a1 += bfhi(v0.x); a2 += bflo(v0.y); a3 += bfhi(v0.y);
        a4 += bflo(v0.z); a5 += bfhi(v0.z); a6 += bflo(v0.w); a7 += bfhi(v0.w);
    }
    if (e < end) {                           // tail: 1..3 edges, per-group predicated
        int idx = e + g;
        bool valid = idx < end;
        int s = csr_src[valid ? idx : end - 1];
        uint4 v = *reinterpret_cast<const uint4*>(h + (size_t)s * HID + fl * 8);
        if (valid) {
            a0 += bflo(v.x); a1 += bfhi(v.x); a2 += bflo(v.y); a3 += bfhi(v.y);
            a4 += bflo(v.z); a5 += bfhi(v.z); a6 += bflo(v.w); a7 += bfhi(v.w);
        }
    }
    a0 += c0; a1 += c1; a2 += c2; a3 += c3;
    a4 += c4; a5 += c5; a6 += c6; a7 += c7;

    // reduce across the 4 groups (lanes differing in bits 4,5)
    a0 += __shfl_xor(a0, 16); a1 += __shfl_xor(a1, 16);
    a2 += __shfl_xor(a2, 16); a3 += __shfl_xor(a3, 16);
    a4 += __shfl_xor(a4, 16); a5 += __shfl_xor(a5, 16);
    a6 += __shfl_xor(a6, 16); a7 += __shfl_xor(a7, 16);
    a0 += __shfl_xor(a0, 32); a1 += __shfl_xor(a1, 32);
    a2 += __shfl_xor(a2, 32); a3 += __shfl_xor(a3, 32);
    a4 += __shfl_xor(a4, 32); a5 += __shfl_xor(a5, 32);
    a6 += __shfl_xor(a6, 32); a7 += __shfl_xor(a7, 32);

    if (g == 0) {
        const float id = invdeg[node];
        uint4 o;
        o.x = (unsigned)f2bfu(a0 * id) | ((unsigned)f2bfu(a1 * id) << 16);
        o.y = (unsigned)f2bfu(a2 * id) | ((unsigned)f2bfu(a3 * id) << 16);
        o.z = (unsigned)f2bfu(a4 * id) | ((unsigned)f2bfu(a5 * id) << 16);
        o.w = (unsigned)f2bfu(a6 * id) | ((unsigned)f2bfu(a7 * id) << 16);
        *reinterpret_cast<uint4*>(agg + (size_t)node * HID + fl * 8) = o;
    }
}

// ---------------- combine via MFMA with LDS-staged weights ----------------
// out = relu(agg @ Wl + bl + h_in @ Wr). 512 thr = 8 waves x 16 rows = 128 rows/block.
// h_out may alias agg: each wave reads only its own 16 rows before writing them.
template<int STORE_F32>
__global__ __launch_bounds__(512)
void k_combine_mfma(const bf16* __restrict__ agg, const bf16* __restrict__ h_in,
                    const bf16* __restrict__ WlT, const bf16* __restrict__ WrT,
                    const float* __restrict__ bl, void* __restrict__ outp) {
    __shared__ bf16 wl_s[HID][HID];   // 32 KB, swizzled chunks
    __shared__ bf16 wr_s[HID][HID];   // 32 KB
    const int wid  = threadIdx.x >> 6;          // 0..7
    const int lane = threadIdx.x & 63;
    const int r0   = blockIdx.x * 128 + wid * 16;
    const int lrow = lane & 15;
    const int kgrp = lane >> 4;

    // stage weights: 128 rows x 16 chunks of 16B, coalesced reads, swizzled LDS writes
    for (int id = threadIdx.x; id < HID * 16; id += 512) {
        const int row = id >> 4, c16 = id & 15;
        const int sc  = c16 ^ (row & 7);
        *reinterpret_cast<uint4*>(&wl_s[row][sc * 8]) =
            *reinterpret_cast<const uint4*>(WlT + (size_t)row * HID + c16 * 8);
        *reinterpret_cast<uint4*>(&wr_s[row][sc * 8]) =
            *reinterpret_cast<const uint4*>(WrT + (size_t)row * HID + c16 * 8);
    }
    __syncthreads();

    f32x4 acc[8];
#pragma unroll
    for (int c = 0; c < 8; c++) acc[c] = (f32x4){0.f, 0.f, 0.f, 0.f};

    const int arow = min(r0 + lrow, N_NODES - 1);

    // m = 0: A = agg, B = wl_s
#pragma unroll
    for (int kk = 0; kk < 4; kk++) {
        const int k0 = kk * 32 + kgrp * 8;
        short8 a = *reinterpret_cast<const short8*>(agg + (size_t)arow * HID + k0);
#pragma unroll
        for (int c = 0; c < 8; c++) {
            const int row = c * 16 + lrow;
            const int kc  = (kk * 4 + kgrp) ^ (lrow & 7);
            short8 b = *reinterpret_cast<const short8*>(&wl_s[row][kc * 8]);
            acc[c] = __builtin_amdgcn_mfma_f32_16x16x32_bf16(a, b, acc[c], 0, 0, 0);
        }
    }
    // m = 1: A = h_in, B = wr_s
#pragma unroll
    for (int kk = 0; kk < 4; kk++) {
        const int k0 = kk * 32 + kgrp * 8;
        short8 a = *reinterpret_cast<const short8*>(h_in + (size_t)arow * HID + k0);
#pragma unroll
        for (int c = 0; c < 8; c++) {
            const int row = c * 16 + lrow;
            const int kc  = (kk * 4 + kgrp) ^ (lrow & 7);
            short8 b = *reinterpret_cast<const short8*>(&wr_s[row][kc * 8]);
            acc[c] = __builtin_amdgcn_mfma_f32_16x16x32_bf16(a, b, acc[c], 0, 0, 0);
        }
    }

#pragma unroll
    for (int c = 0; c < 8; c++) {
        const int col = c * 16 + lrow;
        const float bias = bl[col];
#pragma unroll
        for (int r = 0; r < 4; r++) {
            const int row = r0 + kgrp * 4 + r;
            if (row < N_NODES) {
                float v = fmaxf(acc[c][r] + bias, 0.0f);
                if (STORE_F32)
                    ((float*)outp)[(size_t)row * HID + col] = v;
                else
                    ((bf16*)outp)[(size_t)row * HID + col] = __float2bfloat16(v);
            }
        }
    }
}

extern "C" void kernel_launch(void* const* d_in, const int* in_sizes, int n_in,
                              void* d_out, int out_size, void* d_ws, size_t ws_size,
                              hipStream_t stream) {
    const float* x     = (const float*)d_in[0];
    const int*   ei    = (const int*)d_in[1];
    const float* emb_W = (const float*)d_in[2];
    const float* emb_b = (const float*)d_in[3];
    const float* Wl    = (const float*)d_in[4];
    const float* bl    = (const float*)d_in[5];
    const float* Wr    = (const float*)d_in[6];

    const int* src = ei;
    const int* dst = ei + N_EDGES;

    // workspace layout
    char* ws = (char*)d_ws;
    size_t o = 0;
    int*  degbuf = (int*)(ws + o);  o += ((size_t)N_NODES * 4 + 255) & ~(size_t)255;
    int*  rowcur = (int*)(ws + o);  o += ((size_t)N_NODES * 4 + 255) & ~(size_t)255;
    int*  csrsrc = (int*)(ws + o);  o += ((size_t)N_EDGES * 4 + 255) & ~(size_t)255;
    int*  bsum   = (int*)(ws + o);  o += ((size_t)NCH * 4 + 255) & ~(size_t)255;
    bf16* WlT    = (bf16*)(ws + o); o += ((size_t)NLAYERS * HID * HID * 2 + 255) & ~(size_t)255;
    bf16* WrT    = (bf16*)(ws + o); o += ((size_t)NLAYERS * HID * HID * 2 + 255) & ~(size_t)255;
    bf16* embT   = (bf16*)(ws + o); o += ((size_t)HID * KPAD * 2 + 255) & ~(size_t)255;
    bf16* bufA   = (bf16*)(ws + o); o += ((size_t)N_NODES * HID * 2 + 255) & ~(size_t)255;
    bf16* bufB   = (bf16*)(ws + o);

    // ---- build CSR (scan2 folded into scan3; invdeg fused into scan3) ----
    hipMemsetAsync(degbuf, 0, (size_t)N_NODES * sizeof(int), stream);
    k_deg<<<(N_EDGES + 255) / 256, 256, 0, stream>>>(dst, degbuf);
    k_scan1<<<NCH, SB, 0, stream>>>(degbuf, bsum);
    k_scan3<<<NCH, SB, 0, stream>>>(degbuf, bsum, rowcur);
    const float* invdeg = (const float*)degbuf;
    k_fill<<<(N_EDGES + 255) / 256, 256, 0, stream>>>(src, dst, rowcur, csrsrc);
    // rowcur[n] is now the END offset of row n

    // ---- weight prep (fused) ----
    const int wtotal = NLAYERS * HID * HID + HID * KPAD;
    k_wprep<<<(wtotal + 255) / 256, 256, 0, stream>>>(Wl, Wr, emb_W, WlT, WrT, embT);

    // ---- h0 = relu(x @ emb_W + emb_b) -> bufA (bf16), via MFMA + LDS embT ----
    const int ngrid = (N_NODES + 3) / 4;      // 12500
    const int cgrid = (N_NODES + 127) / 128;  // 391
    k_embed_mfma<<<cgrid, 512, 0, stream>>>(x, embT, emb_b, bufA);

    for (int l = 0; l < NLAYERS; l++) {
        bf16* h_in = (l & 1) ? bufB : bufA;
        bf16* aggb = (l & 1) ? bufA : bufB;
        k_gather<<<ngrid, 256, 0, stream>>>(rowcur, csrsrc, h_in, invdeg, aggb);
        const bf16* wlt = WlT + (size_t)l * HID * HID;
        const bf16* wrt = WrT + (size_t)l * HID * HID;
        const float* blp = bl + (size_t)l * HID;
        if (l == NLAYERS - 1)
            k_combine_mfma<1><<<cgrid, 512, 0, stream>>>(aggb, h_in, wlt, wrt, blp, d_out);
        else
            k_combine_mfma<0><<<cgrid, 512, 0, stream>>>(aggb, h_in, wlt, wrt, blp, aggb);
    }
}